// Round 12
// baseline (239.769 us; speedup 1.0000x reference)
//
#include <hip/hip_runtime.h>
#include <stdint.h>

#define HID 1024
#define NSEQ 1024
#define KREL 1024
#define NHEAD 16
#define DHEAD 64

typedef __attribute__((ext_vector_type(8))) short bhalf8;
typedef __attribute__((ext_vector_type(4))) float floatx4;

__device__ inline uint16_t f2bf(float f) {
  union { float f; uint32_t u; } c; c.f = f;
  uint32_t u = c.u;
  return (uint16_t)((u + 0x7fffu + ((u >> 16) & 1u)) >> 16);
}
__device__ inline uint32_t pkbf(float a, float b) {
  union { float f; uint32_t u; } x, y; x.f = a; y.f = b;
#if __has_builtin(__builtin_amdgcn_perm)
  return __builtin_amdgcn_perm(x.u + 0x8000u, y.u + 0x8000u, 0x03020706u);
#else
  return ((x.u + 0x8000u) >> 16) | ((y.u + 0x8000u) & 0xffff0000u);
#endif
}

// ---------------- fused fp32 -> bf16 casts (8 segments) ----------------
struct Cast8 {
  const float* src[8];
  uint16_t* dst[8];
  int n[8];
};
__global__ __launch_bounds__(256) void cast8_kernel(Cast8 c) {
  int seg = blockIdx.y;
  int n = c.n[seg];
  const float* s = c.src[seg];
  uint16_t* d = c.dst[seg];
  for (int idx = (blockIdx.x * 256 + threadIdx.x) * 4; idx < n; idx += 1024 * 256 * 4) {
    float4 v = *(const float4*)(s + idx);
    ushort4 o;
    o.x = f2bf(v.x); o.y = f2bf(v.y); o.z = f2bf(v.z); o.w = f2bf(v.w);
    *(ushort4*)(d + idx) = o;
  }
}

// ---------------- unified projection GEMM: 128x128 tile, NO-LDS direct-from-L2 (R12) ----------------
// R11 showed proj <=54us and occupancy-insensitive; all operands are L2-resident (weights reused
// 8-16x across blocks, A 8x; per-XCD g-clustering keeps them in the XCD's 4MB L2). LDS staging +
// 2 barriers/K-step was pure overhead (Common-mistake #7). R12: fragments load DIRECT from global,
// zero __syncthreads, compiler free to pipeline loads deep. Grid/tile map/epilogue = R7 4-wave.
// B-frag efficiency: 16 fm-lanes x 2KB stride, 4 kq-lanes fill each 64B line -> 100% of fetched
// bytes used.
struct ProjArgs {
  const uint16_t* A[5];
  const uint16_t* W[5];
  const float* bias[5];
  uint16_t* C[5];
  int trans[5];
};
__global__ __launch_bounds__(256) void proj_gemm(ProjArgs pa) {
  int bidx = blockIdx.x;
  int xcd = bidx & 7, idx = bidx >> 3;
  int g = xcd * 7 + (idx >> 3);
  int nt = idx & 7;
  int z, mt;
  if (g < 24) { z = g >> 3; mt = g & 7; }
  else { int g2 = g - 24; z = 3 + (g2 >> 4); mt = g2 & 15; }
  const uint16_t* A = pa.A[z];
  const uint16_t* W = pa.W[z];
  int i0 = mt * 128, n0 = nt * 128;

  int t = threadIdx.x;
  int lane = t & 63, w = t >> 6;
  int fm = lane & 15, kq = lane >> 4;
  int wm = (w >> 1) * 64, wn = (w & 1) * 64;

  const uint16_t* Ab = A + (size_t)(i0 + wm + fm) * HID + kq * 8;
  const uint16_t* Wb = W + (size_t)(n0 + wn + fm) * HID + kq * 8;

  floatx4 acc[4][4] = {};

  for (int kt = 0; kt < 32; ++kt) {
    int ko = kt * 32;
    bhalf8 af[4], bf[4];
#pragma unroll
    for (int m2 = 0; m2 < 4; ++m2)
      af[m2] = *(const bhalf8*)(Ab + (size_t)(m2 * 16) * HID + ko);
#pragma unroll
    for (int n2 = 0; n2 < 4; ++n2)
      bf[n2] = *(const bhalf8*)(Wb + (size_t)(n2 * 16) * HID + ko);
#pragma unroll
    for (int m2 = 0; m2 < 4; ++m2)
#pragma unroll
      for (int n2 = 0; n2 < 4; ++n2)
        acc[m2][n2] = __builtin_amdgcn_mfma_f32_16x16x32_bf16(af[m2], bf[n2], acc[m2][n2], 0, 0, 0);
  }

  const float* bias = pa.bias[z];
  uint16_t* C = pa.C[z];
  int tr = pa.trans[z];
#pragma unroll
  for (int m2 = 0; m2 < 4; ++m2) {
    int rowb = i0 + wm + m2 * 16 + kq * 4;
#pragma unroll
    for (int n2 = 0; n2 < 4; ++n2) {
      int col = n0 + wn + n2 * 16 + fm;
      float bv = bias[col];
      floatx4 v = acc[m2][n2];
      if (tr) {
        uint2 p = { pkbf(v[0] + bv, v[1] + bv), pkbf(v[2] + bv, v[3] + bv) };
        *(uint2*)(C + (size_t)col * NSEQ + rowb) = p;
      } else {
#pragma unroll
        for (int r = 0; r < 4; ++r)
          C[(size_t)(rowb + r) * HID + col] = f2bf(v[r] + bv);
      }
    }
  }
}

// ---------------- out-proj GEMM: 64x64 tile, NO-LDS direct-from-L2 (R12) ----------------
__global__ __launch_bounds__(256) void out_gemm(const uint16_t* __restrict__ Abf,
                                                const uint16_t* __restrict__ W,
                                                const float* __restrict__ bias,
                                                float* __restrict__ C) {
  int bidx = blockIdx.x;
  int i0 = (bidx >> 4) * 64, n0 = (bidx & 15) * 64;
  int t = threadIdx.x;
  int lane = t & 63, w = t >> 6;
  int fm = lane & 15, kq = lane >> 4;
  int wm = (w >> 1) * 32, wn = (w & 1) * 32;
  const uint16_t* Ab = Abf + (size_t)(i0 + wm + fm) * HID + kq * 8;
  const uint16_t* Wb = W + (size_t)(n0 + wn + fm) * HID + kq * 8;
  floatx4 acc00 = {0,0,0,0}, acc01 = {0,0,0,0}, acc10 = {0,0,0,0}, acc11 = {0,0,0,0};
  for (int kt = 0; kt < 32; ++kt) {
    int ko = kt * 32;
    bhalf8 a0 = *(const bhalf8*)(Ab + ko);
    bhalf8 a1 = *(const bhalf8*)(Ab + (size_t)16 * HID + ko);
    bhalf8 b0 = *(const bhalf8*)(Wb + ko);
    bhalf8 b1 = *(const bhalf8*)(Wb + (size_t)16 * HID + ko);
    acc00 = __builtin_amdgcn_mfma_f32_16x16x32_bf16(a0, b0, acc00, 0, 0, 0);
    acc01 = __builtin_amdgcn_mfma_f32_16x16x32_bf16(a0, b1, acc01, 0, 0, 0);
    acc10 = __builtin_amdgcn_mfma_f32_16x16x32_bf16(a1, b0, acc10, 0, 0, 0);
    acc11 = __builtin_amdgcn_mfma_f32_16x16x32_bf16(a1, b1, acc11, 0, 0, 0);
  }
  int rb0 = kq * 4;
#define EPO(ACC, SM, SN)                                                   \
  {                                                                        \
    int rowb = i0 + wm + (SM)*16 + rb0;                                    \
    int col = n0 + wn + (SN)*16 + fm;                                      \
    float bv_ = bias[col];                                                 \
    _Pragma("unroll")                                                      \
    for (int rr = 0; rr < 4; ++rr)                                         \
      C[(size_t)(rowb + rr) * HID + col] = ACC[rr] + bv_;                  \
  }
  EPO(acc00, 0, 0) EPO(acc01, 0, 1) EPO(acc10, 1, 0) EPO(acc11, 1, 1)
#undef EPO
}

// ---------------- MFMA fused attention: R7/R11 version UNCHANGED (54.8us measured) ----------------
__global__ __launch_bounds__(256) void attn_kernel(const uint16_t* __restrict__ qg,
                                                   const uint16_t* __restrict__ kg,
                                                   const uint16_t* __restrict__ vtg,
                                                   const uint16_t* __restrict__ pkg,
                                                   const uint16_t* __restrict__ pqg,
                                                   uint16_t* __restrict__ ctx) {
  const float RSCALE = 0.07216878364870323f;  // 1/sqrt(192)
  __shared__ uint16_t Qs[32][72];
  __shared__ uint16_t Ks[32][72];
  __shared__ uint16_t Vt[64][40];
  __shared__ float C2Ps[2][32][68];   // pre-shifted: [i][j] where j = (i - rr + 31) & 63
  __shared__ float P2C[2][32][68];    // logical [krow][rr]
  __shared__ float Sqk[2][32][36];
  __shared__ uint16_t Pbf[32][40];
  __shared__ float m_sm[32], l_sm[32], al_sm[32];

  int t = threadIdx.x;
  int lane = t & 63, w = t >> 6;
  int fm = lane & 15;
  int kq = lane >> 4;

  int b = blockIdx.x;
  int xcd = b & 7, slot = b >> 3;
  int h = xcd * 2 + (slot & 1);
  int i0 = (slot >> 1) * 32;
  int cb = h * DHEAD;

  {
    int r = t >> 3, chq = (t & 7) * 8;
    *(uint4*)(&Qs[r][chq]) = *(const uint4*)(qg + (size_t)(i0 + r) * HID + cb + chq);
  }
  if (t < 32) { m_sm[t] = -1e30f; l_sm[t] = 0.f; }

  floatx4 opv0 = {0,0,0,0}, opv1 = {0,0,0,0};
  int wn = w * 16;
  int smt = w >> 1, snt = w & 1;
  int i2 = t >> 3, jj4 = (t & 7) * 4;

  int pr = t >> 3, pch = (t & 7) * 8;
  int rV = t >> 2, cV = (t & 3) * 8;
  const uint16_t* kb = kg + cb + pch;
  const uint16_t* vb = vtg + (size_t)(cb + rV) * HID + cV;

  int ntb = (w & 1) * 2;
  int brow_f = ntb * 16 + fm;
  const uint16_t* bgp = ((w < 2) ? pkg : pqg) + cb + kq * 8;
  int cbase = 31 - brow_f + kq * 4;

  uint4 rk, rv;
  bhalf8 nbA0, nbA1, nbB0, nbB1;

#define STAGE1(BUF, BA0, BA1, BB0, BB1)                                          \
  do {                                                                           \
    if (w < 2) {                                                                 \
      _Pragma("unroll")                                                          \
      for (int mt = 0; mt < 2; ++mt) {                                           \
        bhalf8 a0 = *(bhalf8*)(&Qs[mt * 16 + fm][kq * 8]);                       \
        bhalf8 a1 = *(bhalf8*)(&Qs[mt * 16 + fm][kq * 8 + 32]);                  \
        floatx4 ac0 = {0,0,0,0}, ac1 = {0,0,0,0};                                \
        ac0 = __builtin_amdgcn_mfma_f32_16x16x32_bf16(a0, BA0, ac0, 0, 0, 0);    \
        ac0 = __builtin_amdgcn_mfma_f32_16x16x32_bf16(a1, BA1, ac0, 0, 0, 0);    \
        ac1 = __builtin_amdgcn_mfma_f32_16x16x32_bf16(a0, BB0, ac1, 0, 0, 0);    \
        ac1 = __builtin_amdgcn_mfma_f32_16x16x32_bf16(a1, BB1, ac1, 0, 0, 0);    \
        _Pragma("unroll")                                                        \
        for (int r = 0; r < 4; ++r) {                                            \
          int i = mt * 16 + kq * 4 + r;                                          \
          C2Ps[BUF][i][(cbase + mt * 16 + r) & 63] = ac0[r];                     \
          C2Ps[BUF][i][(cbase + mt * 16 + r - 16) & 63] = ac1[r];                \
        }                                                                        \
      }                                                                          \
    } else {                                                                     \
      _Pragma("unroll")                                                          \
      for (int mt = 0; mt < 2; ++mt) {                                           \
        bhalf8 a0 = *(bhalf8*)(&Ks[mt * 16 + fm][kq * 8]);                       \
        bhalf8 a1 = *(bhalf8*)(&Ks[mt * 16 + fm][kq * 8 + 32]);                  \
        floatx4 ac0 = {0,0,0,0}, ac1 = {0,0,0,0};                                \
        ac0 = __builtin_amdgcn_mfma_f32_16x16x32_bf16(a0, BA0, ac0, 0, 0, 0);    \
        ac0 = __builtin_amdgcn_mfma_f32_16x16x32_bf16(a1, BA1, ac0, 0, 0, 0);    \
        ac1 = __builtin_amdgcn_mfma_f32_16x16x32_bf16(a0, BB0, ac1, 0, 0, 0);    \
        ac1 = __builtin_amdgcn_mfma_f32_16x16x32_bf16(a1, BB1, ac1, 0, 0, 0);    \
        _Pragma("unroll")                                                        \
        for (int r = 0; r < 4; ++r) {                                            \
          int jr = mt * 16 + kq * 4 + r;                                         \
          P2C[BUF][jr][brow_f] = ac0[r];                                         \
          P2C[BUF][jr][brow_f + 16] = ac1[r];                                    \
        }                                                                        \
      }                                                                          \
    }                                                                            \
    {                                                                            \
      bhalf8 qa0 = *(bhalf8*)(&Qs[smt * 16 + fm][kq * 8]);                       \
      bhalf8 qa1 = *(bhalf8*)(&Qs[smt * 16 + fm][kq * 8 + 32]);                  \
      bhalf8 kb0 = *(bhalf8*)(&Ks[snt * 16 + fm][kq * 8]);                       \
      bhalf8 kb1 = *(bhalf8*)(&Ks[snt * 16 + fm][kq * 8 + 32]);                  \
      floatx4 sacc = {0,0,0,0};                                                  \
      sacc = __builtin_amdgcn_mfma_f32_16x16x32_bf16(qa0, kb0, sacc, 0, 0, 0);   \
      sacc = __builtin_amdgcn_mfma_f32_16x16x32_bf16(qa1, kb1, sacc, 0, 0, 0);   \
      _Pragma("unroll")                                                          \
      for (int r = 0; r < 4; ++r)                                                \
        Sqk[BUF][smt * 16 + kq * 4 + r][snt * 16 + fm] = sacc[r];                \
    }                                                                            \
  } while (0)

  rk = *(const uint4*)(kb);
  rv = *(const uint4*)(vb);
  *(uint4*)(&Ks[pr][pch]) = rk;
  *(uint4*)(&Vt[rV][cV]) = rv;
  __syncthreads();
  rk = *(const uint4*)(kb + (size_t)(32 + pr) * HID);
  rv = *(const uint4*)(vb + 32);
  {
    int rbase = KREL + i0 - 31;
    int r0 = rbase + brow_f;      if (r0 > 2047) r0 = 2047;
    int r1 = rbase + brow_f + 16; if (r1 > 2047) r1 = 2047;
    bhalf8 tA0 = *(const bhalf8*)(bgp + ((size_t)r0 << 10));
    bhalf8 tA1 = *(const bhalf8*)(bgp + ((size_t)r0 << 10) + 32);
    bhalf8 tB0 = *(const bhalf8*)(bgp + ((size_t)r1 << 10));
    bhalf8 tB1 = *(const bhalf8*)(bgp + ((size_t)r1 << 10) + 32);
    STAGE1(0, tA0, tA1, tB0, tB1);
  }
  __syncthreads();
  {
    *(uint4*)(&Ks[pr][pch]) = rk;
    rk = *(const uint4*)(kb + (size_t)(64 + pr) * HID);
    int rb1 = KREL + i0 - 63;
    int r0 = rb1 + brow_f;
    nbA0 = *(const bhalf8*)(bgp + ((size_t)r0 << 10));
    nbA1 = *(const bhalf8*)(bgp + ((size_t)r0 << 10) + 32);
    nbB0 = *(const bhalf8*)(bgp + ((size_t)(r0 + 16) << 10));
    nbB1 = *(const bhalf8*)(bgp + ((size_t)(r0 + 16) << 10) + 32);
  }
  __syncthreads();

  for (int jt = 0; jt < NSEQ / 32; ++jt) {
    int cur = jt & 1;

    float4 v_sqk = *(const float4*)(&Sqk[cur][i2][jj4]);
    float4 v_c2p = *(const float4*)(&C2Ps[cur][i2][jj4]);
    float p0 = P2C[cur][jj4 + 0][i2 - jj4 + 31];
    float p1 = P2C[cur][jj4 + 1][i2 - jj4 + 30];
    float p2 = P2C[cur][jj4 + 2][i2 - jj4 + 29];
    float p3 = P2C[cur][jj4 + 3][i2 - jj4 + 28];

    if (jt < 31) {
      int bi = cur ^ 1;
      STAGE1(bi, nbA0, nbA1, nbB0, nbB1);
    }

    {
      float sv0 = (v_sqk.x + v_c2p.x + p0) * RSCALE;
      float sv1 = (v_sqk.y + v_c2p.y + p1) * RSCALE;
      float sv2 = (v_sqk.z + v_c2p.z + p2) * RSCALE;
      float sv3 = (v_sqk.w + v_c2p.w + p3) * RSCALE;
      float mx = fmaxf(fmaxf(sv0, sv1), fmaxf(sv2, sv3));
      mx = fmaxf(mx, __shfl_xor(mx, 1));
      mx = fmaxf(mx, __shfl_xor(mx, 2));
      mx = fmaxf(mx, __shfl_xor(mx, 4));
      float m_old = m_sm[i2];
      float m_new = fmaxf(m_old, mx);
      float al = __expf(m_old - m_new);
      float e0 = __expf(sv0 - m_new);
      float e1 = __expf(sv1 - m_new);
      float e2 = __expf(sv2 - m_new);
      float e3 = __expf(sv3 - m_new);
      uint2 pk2v;
      pk2v.x = (uint32_t)f2bf(e0) | ((uint32_t)f2bf(e1) << 16);
      pk2v.y = (uint32_t)f2bf(e2) | ((uint32_t)f2bf(e3) << 16);
      *(uint2*)(&Pbf[i2][jj4]) = pk2v;
      float ts = (e0 + e1) + (e2 + e3);
      ts += __shfl_xor(ts, 1);
      ts += __shfl_xor(ts, 2);
      ts += __shfl_xor(ts, 4);
      if (jj4 == 0) { m_sm[i2] = m_new; l_sm[i2] = l_sm[i2] * al + ts; al_sm[i2] = al; }
    }
    __syncthreads();

    {
      floatx4 al0 = *(const floatx4*)(&al_sm[kq * 4]);
      floatx4 al1 = *(const floatx4*)(&al_sm[16 + kq * 4]);
#pragma unroll
      for (int r = 0; r < 4; ++r) {
        opv0[r] *= al0[r];
        opv1[r] *= al1[r];
      }
      bhalf8 vbf = *(bhalf8*)(&Vt[wn + fm][kq * 8]);
      bhalf8 pa0 = *(bhalf8*)(&Pbf[fm][kq * 8]);
      bhalf8 pa1 = *(bhalf8*)(&Pbf[16 + fm][kq * 8]);
      opv0 = __builtin_amdgcn_mfma_f32_16x16x32_bf16(pa0, vbf, opv0, 0, 0, 0);
      opv1 = __builtin_amdgcn_mfma_f32_16x16x32_bf16(pa1, vbf, opv1, 0, 0, 0);
      if (jt < 31) *(uint4*)(&Vt[rV][cV]) = rv;
      if (jt < 30) rv = *(const uint4*)(vb + (jt + 2) * 32);
    }
    if (jt < 30) {
      *(uint4*)(&Ks[pr][pch]) = rk;
    }
    if (jt < 29) {
      rk = *(const uint4*)(kb + (size_t)((jt + 3) * 32 + pr) * HID);
    }
    if (jt < 30) {
      int rb = KREL + i0 - (jt + 2) * 32 - 31;
      int r0 = rb + brow_f;
      nbA0 = *(const bhalf8*)(bgp + ((size_t)r0 << 10));
      nbA1 = *(const bhalf8*)(bgp + ((size_t)r0 << 10) + 32);
      nbB0 = *(const bhalf8*)(bgp + ((size_t)(r0 + 16) << 10));
      nbB1 = *(const bhalf8*)(bgp + ((size_t)(r0 + 16) << 10) + 32);
    }
    __syncthreads();
  }
#undef STAGE1

  {
    floatx4 l0 = *(const floatx4*)(&l_sm[kq * 4]);
    floatx4 l1 = *(const floatx4*)(&l_sm[16 + kq * 4]);
#pragma unroll
    for (int r = 0; r < 4; ++r) {
      int ia = kq * 4 + r, ib = 16 + kq * 4 + r;
      ctx[(size_t)(i0 + ia) * HID + cb + wn + fm] = f2bf(opv0[r] / l0[r]);
      ctx[(size_t)(i0 + ib) * HID + cb + wn + fm] = f2bf(opv1[r] / l1[r]);
    }
  }
}

// ---------------- residual + LayerNorm ----------------
__global__ __launch_bounds__(256) void ln_kernel(const float* __restrict__ xin,
                                                 const float* __restrict__ hs,
                                                 const float* __restrict__ g,
                                                 const float* __restrict__ b,
                                                 float* __restrict__ y) {
  int row = blockIdx.x, t = threadIdx.x;
  int c = t * 4;
  float4 a = *(const float4*)(xin + (size_t)row * HID + c);
  float4 hv = *(const float4*)(hs + (size_t)row * HID + c);
  float x0 = a.x + hv.x, x1 = a.y + hv.y, x2 = a.z + hv.z, x3 = a.w + hv.w;
  float s = x0 + x1 + x2 + x3;
  float sq = x0 * x0 + x1 * x1 + x2 * x2 + x3 * x3;
  for (int off = 32; off; off >>= 1) {
    s += __shfl_xor(s, off);
    sq += __shfl_xor(sq, off);
  }
  __shared__ float rs[4], rq[4];
  int w = t >> 6, lane = t & 63;
  if (lane == 0) { rs[w] = s; rq[w] = sq; }
  __syncthreads();
  s = rs[0] + rs[1] + rs[2] + rs[3];
  sq = rq[0] + rq[1] + rq[2] + rq[3];
  float mu = s * (1.0f / HID);
  float var = sq * (1.0f / HID) - mu * mu;
  float rstd = rsqrtf(var + 1e-7f);
  float4 gg = *(const float4*)(g + c);
  float4 bb = *(const float4*)(b + c);
  float4 out;
  out.x = (x0 - mu) * rstd * gg.x + bb.x;
  out.y = (x1 - mu) * rstd * gg.y + bb.y;
  out.z = (x2 - mu) * rstd * gg.z + bb.z;
  out.w = (x3 - mu) * rstd * gg.w + bb.w;
  *(float4*)(y + (size_t)row * HID + c) = out;
}

extern "C" void kernel_launch(void* const* d_in, const int* in_sizes, int n_in,
                              void* d_out, int out_size, void* d_ws, size_t ws_size,
                              hipStream_t stream) {
  const float* hs  = (const float*)d_in[0];
  const float* rel = (const float*)d_in[1];
  const float* Wq  = (const float*)d_in[2];  const float* bq  = (const float*)d_in[3];
  const float* Wk  = (const float*)d_in[4];  const float* bk  = (const float*)d_in[5];
  const float* Wv  = (const float*)d_in[6];  const float* bv  = (const float*)d_in[7];
  const float* Wpk = (const float*)d_in[8];  const float* bpk = (const float*)d_in[9];
  const float* Wpq = (const float*)d_in[10]; const float* bpq = (const float*)d_in[11];
  const float* Wo  = (const float*)d_in[12]; const float* bo  = (const float*)d_in[13];
  const float* lng = (const float*)d_in[14]; const float* lnb = (const float*)d_in[15];

  char* ws = (char*)d_ws;
  const size_t MB = 1024 * 1024;
  uint16_t* q_bf   = (uint16_t*)(ws + 0 * MB);
  uint16_t* k_bf   = (uint16_t*)(ws + 2 * MB);
  uint16_t* vt_bf  = (uint16_t*)(ws + 4 * MB);   // transposed [d][i]
  uint16_t* pk_bf  = (uint16_t*)(ws + 6 * MB);
  uint16_t* pq_bf  = (uint16_t*)(ws + 10 * MB);
  uint16_t* ctx_bf = (uint16_t*)(ws + 14 * MB);
  float*    out_f  = (float*)   (ws + 16 * MB);
  uint16_t* hs_bf  = (uint16_t*)(ws + 20 * MB);
  uint16_t* rel_bf = (uint16_t*)(ws + 22 * MB);
  uint16_t* Wq_bf  = (uint16_t*)(ws + 26 * MB);
  uint16_t* Wk_bf  = (uint16_t*)(ws + 28 * MB);
  uint16_t* Wv_bf  = (uint16_t*)(ws + 30 * MB);
  uint16_t* Wpk_bf = (uint16_t*)(ws + 32 * MB);
  uint16_t* Wpq_bf = (uint16_t*)(ws + 34 * MB);
  uint16_t* Wo_bf  = (uint16_t*)(ws + 36 * MB);  // total 38 MB

  dim3 blk(256);

  Cast8 c8;
  c8.src[0] = hs;  c8.dst[0] = hs_bf;  c8.n[0] = 1024 * 1024;
  c8.src[1] = rel; c8.dst[1] = rel_bf; c8.n[1] = 2048 * 1024;
  c8.src[2] = Wq;  c8.dst[2] = Wq_bf;  c8.n[2] = 1024 * 1024;
  c8.src[3] = Wk;  c8.dst[3] = Wk_bf;  c8.n[3] = 1024 * 1024;
  c8.src[4] = Wv;  c8.dst[4] = Wv_bf;  c8.n[4] = 1024 * 1024;
  c8.src[5] = Wpk; c8.dst[5] = Wpk_bf; c8.n[5] = 1024 * 1024;
  c8.src[6] = Wpq; c8.dst[6] = Wpq_bf; c8.n[6] = 1024 * 1024;
  c8.src[7] = Wo;  c8.dst[7] = Wo_bf;  c8.n[7] = 1024 * 1024;
  cast8_kernel<<<dim3(1024, 8), blk, 0, stream>>>(c8);

  ProjArgs pa;
  pa.A[0] = hs_bf;  pa.A[1] = hs_bf;  pa.A[2] = hs_bf;  pa.A[3] = rel_bf; pa.A[4] = rel_bf;
  pa.W[0] = Wq_bf;  pa.W[1] = Wk_bf;  pa.W[2] = Wv_bf;  pa.W[3] = Wpk_bf; pa.W[4] = Wpq_bf;
  pa.bias[0] = bq;  pa.bias[1] = bk;  pa.bias[2] = bv;  pa.bias[3] = bpk; pa.bias[4] = bpq;
  pa.C[0] = q_bf; pa.C[1] = k_bf; pa.C[2] = vt_bf; pa.C[3] = pk_bf; pa.C[4] = pq_bf;
  pa.trans[0] = 0; pa.trans[1] = 0; pa.trans[2] = 1; pa.trans[3] = 0; pa.trans[4] = 0;
  proj_gemm<<<dim3(448), blk, 0, stream>>>(pa);

  attn_kernel<<<dim3(512), blk, 0, stream>>>(q_bf, k_bf, vt_bf, pk_bf, pq_bf, ctx_bf);

  out_gemm<<<dim3(256), blk, 0, stream>>>(ctx_bf, Wo_bf, bo, out_f);

  ln_kernel<<<dim3(1024), blk, 0, stream>>>(out_f, hs, lng, lnb, (float*)d_out);
}

// Round 13
// 196.023 us; speedup vs baseline: 1.2232x; 1.2232x over previous
//
#include <hip/hip_runtime.h>
#include <stdint.h>

#define HID 1024
#define NSEQ 1024
#define KREL 1024
#define NHEAD 16
#define DHEAD 64

typedef __attribute__((ext_vector_type(8))) short bhalf8;
typedef __attribute__((ext_vector_type(4))) float floatx4;

__device__ inline uint16_t f2bf(float f) {
  union { float f; uint32_t u; } c; c.f = f;
  uint32_t u = c.u;
  return (uint16_t)((u + 0x7fffu + ((u >> 16) & 1u)) >> 16);
}
__device__ inline uint32_t pkbf(float a, float b) {
  union { float f; uint32_t u; } x, y; x.f = a; y.f = b;
#if __has_builtin(__builtin_amdgcn_perm)
  return __builtin_amdgcn_perm(x.u + 0x8000u, y.u + 0x8000u, 0x03020706u);
#else
  return ((x.u + 0x8000u) >> 16) | ((y.u + 0x8000u) & 0xffff0000u);
#endif
}
// HW packed f32x2 -> bf16x2 (RNE); src0 -> low 16 bits. 1 instr/pair (T12 recipe).
__device__ inline uint32_t cvtpk(float lo, float hi) {
  uint32_t r;
  asm("v_cvt_pk_bf16_f32 %0, %1, %2" : "=v"(r) : "v"(lo), "v"(hi));
  return r;
}
__device__ inline uint4 cvt8(float4 a, float4 b) {
  uint4 r;
  r.x = cvtpk(a.x, a.y); r.y = cvtpk(a.z, a.w);
  r.z = cvtpk(b.x, b.y); r.w = cvtpk(b.z, b.w);
  return r;
}

// ---------------- unified projection GEMM: 128x128 tile, BK=32, 8 waves, fp32-in (R13) ----------------
// R11's measured-best 8-wave LDS structure; ONLY delta: A/W read as fp32 and converted during
// staging with v_cvt_pk_bf16_f32 (4 pairs/matrix/thread = 8 VALU ops/K-step -- 20x cheaper than
// R2's failed bit-twiddle fusion). cast8_kernel deleted.
struct ProjArgs {
  const float* A[5];
  const float* W[5];
  const float* bias[5];
  uint16_t* C[5];
  int trans[5];
};
__global__ __launch_bounds__(512) void proj_gemm(ProjArgs pa) {
  __shared__ uint16_t a_s[2][128 * 40];
  __shared__ uint16_t b_s[2][128 * 40];
  int bidx = blockIdx.x;
  int xcd = bidx & 7, idx = bidx >> 3;
  int g = xcd * 7 + (idx >> 3);
  int nt = idx & 7;
  int z, mt;
  if (g < 24) { z = g >> 3; mt = g & 7; }
  else { int g2 = g - 24; z = 3 + (g2 >> 4); mt = g2 & 15; }
  const float* A = pa.A[z];
  const float* W = pa.W[z];
  int i0 = mt * 128, n0 = nt * 128;

  int t = threadIdx.x;
  int lane = t & 63, w = t >> 6;       // w in 0..7
  int fm = lane & 15, kq = lane >> 4;
  int wm = (w >> 2) * 64, wn = (w & 3) * 32;

  int ra = t >> 2, ca = (t & 3) * 8;   // 128 rows x 32 cols, 8 elem/thread
  const float* Ap = A + (size_t)(i0 + ra) * HID + ca;
  const float* Wp = W + (size_t)(n0 + ra) * HID + ca;

  floatx4 acc[4][2] = {};

  float4 fa0 = *(const float4*)(Ap);
  float4 fa1 = *(const float4*)(Ap + 4);
  float4 fb0 = *(const float4*)(Wp);
  float4 fb1 = *(const float4*)(Wp + 4);
  *(uint4*)(&a_s[0][ra * 40 + ca]) = cvt8(fa0, fa1);
  *(uint4*)(&b_s[0][ra * 40 + ca]) = cvt8(fb0, fb1);

  for (int kt = 0; kt < 32; ++kt) {
    __syncthreads();
    int cur = kt & 1;
    if (kt < 31) {
      int ko = (kt + 1) * 32;
      fa0 = *(const float4*)(Ap + ko);
      fa1 = *(const float4*)(Ap + ko + 4);
      fb0 = *(const float4*)(Wp + ko);
      fb1 = *(const float4*)(Wp + ko + 4);
    }
    const uint16_t* as = &a_s[cur][0];
    const uint16_t* bs = &b_s[cur][0];
    bhalf8 af[4], bf[2];
#pragma unroll
    for (int m2 = 0; m2 < 4; ++m2)
      af[m2] = *(bhalf8*)(as + (wm + m2 * 16 + fm) * 40 + kq * 8);
#pragma unroll
    for (int n2 = 0; n2 < 2; ++n2)
      bf[n2] = *(bhalf8*)(bs + (wn + n2 * 16 + fm) * 40 + kq * 8);
#pragma unroll
    for (int m2 = 0; m2 < 4; ++m2)
#pragma unroll
      for (int n2 = 0; n2 < 2; ++n2)
        acc[m2][n2] = __builtin_amdgcn_mfma_f32_16x16x32_bf16(af[m2], bf[n2], acc[m2][n2], 0, 0, 0);
    if (kt < 31) {
      int nxt = cur ^ 1;
      *(uint4*)(&a_s[nxt][ra * 40 + ca]) = cvt8(fa0, fa1);
      *(uint4*)(&b_s[nxt][ra * 40 + ca]) = cvt8(fb0, fb1);
    }
  }

  const float* bias = pa.bias[z];
  uint16_t* C = pa.C[z];
  int tr = pa.trans[z];
#pragma unroll
  for (int m2 = 0; m2 < 4; ++m2) {
    int rowb = i0 + wm + m2 * 16 + kq * 4;
#pragma unroll
    for (int n2 = 0; n2 < 2; ++n2) {
      int col = n0 + wn + n2 * 16 + fm;
      float bv = bias[col];
      floatx4 v = acc[m2][n2];
      if (tr) {
        uint2 p = { pkbf(v[0] + bv, v[1] + bv), pkbf(v[2] + bv, v[3] + bv) };
        *(uint2*)(C + (size_t)col * NSEQ + rowb) = p;
      } else {
#pragma unroll
        for (int r = 0; r < 4; ++r)
          C[(size_t)(rowb + r) * HID + col] = f2bf(v[r] + bv);
      }
    }
  }
}

// ---------------- out-proj GEMM: R7 LDS structure; Wo read fp32 + cvt_pk staging (R13) ----------------
__global__ __launch_bounds__(256) void out_gemm(const uint16_t* __restrict__ Abf,
                                                const float* __restrict__ W,
                                                const float* __restrict__ bias,
                                                float* __restrict__ C) {
  __shared__ uint16_t a_s[2][64 * 40];
  __shared__ uint16_t b_s[2][64 * 40];
  int bidx = blockIdx.x;
  int i0 = (bidx >> 4) * 64, n0 = (bidx & 15) * 64;
  int t = threadIdx.x;
  int lane = t & 63, w = t >> 6;
  int fm = lane & 15, kq = lane >> 4;
  int wm = (w >> 1) * 32, wn = (w & 1) * 32;
  int ra = t >> 2, ca = (t & 3) * 8;
  const uint16_t* Ap = Abf + (size_t)(i0 + ra) * HID + ca;
  const float* Wp = W + (size_t)(n0 + ra) * HID + ca;
  floatx4 acc00 = {0,0,0,0}, acc01 = {0,0,0,0}, acc10 = {0,0,0,0}, acc11 = {0,0,0,0};
  uint4 ua = *(const uint4*)(Ap);
  float4 fw0 = *(const float4*)(Wp);
  float4 fw1 = *(const float4*)(Wp + 4);
  *(uint4*)(&a_s[0][ra * 40 + ca]) = ua;
  *(uint4*)(&b_s[0][ra * 40 + ca]) = cvt8(fw0, fw1);
  for (int kt = 0; kt < 32; ++kt) {
    __syncthreads();
    int cur = kt & 1;
    if (kt < 31) {
      int ko = (kt + 1) * 32;
      ua = *(const uint4*)(Ap + ko);
      fw0 = *(const float4*)(Wp + ko);
      fw1 = *(const float4*)(Wp + ko + 4);
    }
    const uint16_t* as = &a_s[cur][0];
    const uint16_t* bs = &b_s[cur][0];
    bhalf8 a0 = *(bhalf8*)(as + (wm + fm) * 40 + kq * 8);
    bhalf8 a1 = *(bhalf8*)(as + (wm + 16 + fm) * 40 + kq * 8);
    bhalf8 b0 = *(bhalf8*)(bs + (wn + fm) * 40 + kq * 8);
    bhalf8 b1 = *(bhalf8*)(bs + (wn + 16 + fm) * 40 + kq * 8);
    acc00 = __builtin_amdgcn_mfma_f32_16x16x32_bf16(a0, b0, acc00, 0, 0, 0);
    acc01 = __builtin_amdgcn_mfma_f32_16x16x32_bf16(a0, b1, acc01, 0, 0, 0);
    acc10 = __builtin_amdgcn_mfma_f32_16x16x32_bf16(a1, b0, acc10, 0, 0, 0);
    acc11 = __builtin_amdgcn_mfma_f32_16x16x32_bf16(a1, b1, acc11, 0, 0, 0);
    if (kt < 31) {
      int nxt = cur ^ 1;
      *(uint4*)(&a_s[nxt][ra * 40 + ca]) = ua;
      *(uint4*)(&b_s[nxt][ra * 40 + ca]) = cvt8(fw0, fw1);
    }
  }
  int rb0 = kq * 4;
#define EPO(ACC, SM, SN)                                                   \
  {                                                                        \
    int rowb = i0 + wm + (SM)*16 + rb0;                                    \
    int col = n0 + wn + (SN)*16 + fm;                                      \
    float bv_ = bias[col];                                                 \
    _Pragma("unroll")                                                      \
    for (int rr = 0; rr < 4; ++rr)                                         \
      C[(size_t)(rowb + rr) * HID + col] = ACC[rr] + bv_;                  \
  }
  EPO(acc00, 0, 0) EPO(acc01, 0, 1) EPO(acc10, 1, 0) EPO(acc11, 1, 1)
#undef EPO
}

// ---------------- MFMA fused attention: R7/R11 version UNCHANGED (54.8us measured) ----------------
__global__ __launch_bounds__(256) void attn_kernel(const uint16_t* __restrict__ qg,
                                                   const uint16_t* __restrict__ kg,
                                                   const uint16_t* __restrict__ vtg,
                                                   const uint16_t* __restrict__ pkg,
                                                   const uint16_t* __restrict__ pqg,
                                                   uint16_t* __restrict__ ctx) {
  const float RSCALE = 0.07216878364870323f;  // 1/sqrt(192)
  __shared__ uint16_t Qs[32][72];
  __shared__ uint16_t Ks[32][72];
  __shared__ uint16_t Vt[64][40];
  __shared__ float C2Ps[2][32][68];   // pre-shifted: [i][j] where j = (i - rr + 31) & 63
  __shared__ float P2C[2][32][68];    // logical [krow][rr]
  __shared__ float Sqk[2][32][36];
  __shared__ uint16_t Pbf[32][40];
  __shared__ float m_sm[32], l_sm[32], al_sm[32];

  int t = threadIdx.x;
  int lane = t & 63, w = t >> 6;
  int fm = lane & 15;
  int kq = lane >> 4;

  int b = blockIdx.x;
  int xcd = b & 7, slot = b >> 3;
  int h = xcd * 2 + (slot & 1);
  int i0 = (slot >> 1) * 32;
  int cb = h * DHEAD;

  {
    int r = t >> 3, chq = (t & 7) * 8;
    *(uint4*)(&Qs[r][chq]) = *(const uint4*)(qg + (size_t)(i0 + r) * HID + cb + chq);
  }
  if (t < 32) { m_sm[t] = -1e30f; l_sm[t] = 0.f; }

  floatx4 opv0 = {0,0,0,0}, opv1 = {0,0,0,0};
  int wn = w * 16;
  int smt = w >> 1, snt = w & 1;
  int i2 = t >> 3, jj4 = (t & 7) * 4;

  int pr = t >> 3, pch = (t & 7) * 8;
  int rV = t >> 2, cV = (t & 3) * 8;
  const uint16_t* kb = kg + cb + pch;
  const uint16_t* vb = vtg + (size_t)(cb + rV) * HID + cV;

  int ntb = (w & 1) * 2;
  int brow_f = ntb * 16 + fm;
  const uint16_t* bgp = ((w < 2) ? pkg : pqg) + cb + kq * 8;
  int cbase = 31 - brow_f + kq * 4;

  uint4 rk, rv;
  bhalf8 nbA0, nbA1, nbB0, nbB1;

#define STAGE1(BUF, BA0, BA1, BB0, BB1)                                          \
  do {                                                                           \
    if (w < 2) {                                                                 \
      _Pragma("unroll")                                                          \
      for (int mt = 0; mt < 2; ++mt) {                                           \
        bhalf8 a0 = *(bhalf8*)(&Qs[mt * 16 + fm][kq * 8]);                       \
        bhalf8 a1 = *(bhalf8*)(&Qs[mt * 16 + fm][kq * 8 + 32]);                  \
        floatx4 ac0 = {0,0,0,0}, ac1 = {0,0,0,0};                                \
        ac0 = __builtin_amdgcn_mfma_f32_16x16x32_bf16(a0, BA0, ac0, 0, 0, 0);    \
        ac0 = __builtin_amdgcn_mfma_f32_16x16x32_bf16(a1, BA1, ac0, 0, 0, 0);    \
        ac1 = __builtin_amdgcn_mfma_f32_16x16x32_bf16(a0, BB0, ac1, 0, 0, 0);    \
        ac1 = __builtin_amdgcn_mfma_f32_16x16x32_bf16(a1, BB1, ac1, 0, 0, 0);    \
        _Pragma("unroll")                                                        \
        for (int r = 0; r < 4; ++r) {                                            \
          int i = mt * 16 + kq * 4 + r;                                          \
          C2Ps[BUF][i][(cbase + mt * 16 + r) & 63] = ac0[r];                     \
          C2Ps[BUF][i][(cbase + mt * 16 + r - 16) & 63] = ac1[r];                \
        }                                                                        \
      }                                                                          \
    } else {                                                                     \
      _Pragma("unroll")                                                          \
      for (int mt = 0; mt < 2; ++mt) {                                           \
        bhalf8 a0 = *(bhalf8*)(&Ks[mt * 16 + fm][kq * 8]);                       \
        bhalf8 a1 = *(bhalf8*)(&Ks[mt * 16 + fm][kq * 8 + 32]);                  \
        floatx4 ac0 = {0,0,0,0}, ac1 = {0,0,0,0};                                \
        ac0 = __builtin_amdgcn_mfma_f32_16x16x32_bf16(a0, BA0, ac0, 0, 0, 0);    \
        ac0 = __builtin_amdgcn_mfma_f32_16x16x32_bf16(a1, BA1, ac0, 0, 0, 0);    \
        ac1 = __builtin_amdgcn_mfma_f32_16x16x32_bf16(a0, BB0, ac1, 0, 0, 0);    \
        ac1 = __builtin_amdgcn_mfma_f32_16x16x32_bf16(a1, BB1, ac1, 0, 0, 0);    \
        _Pragma("unroll")                                                        \
        for (int r = 0; r < 4; ++r) {                                            \
          int jr = mt * 16 + kq * 4 + r;                                         \
          P2C[BUF][jr][brow_f] = ac0[r];                                         \
          P2C[BUF][jr][brow_f + 16] = ac1[r];                                    \
        }                                                                        \
      }                                                                          \
    }                                                                            \
    {                                                                            \
      bhalf8 qa0 = *(bhalf8*)(&Qs[smt * 16 + fm][kq * 8]);                       \
      bhalf8 qa1 = *(bhalf8*)(&Qs[smt * 16 + fm][kq * 8 + 32]);                  \
      bhalf8 kb0 = *(bhalf8*)(&Ks[snt * 16 + fm][kq * 8]);                       \
      bhalf8 kb1 = *(bhalf8*)(&Ks[snt * 16 + fm][kq * 8 + 32]);                  \
      floatx4 sacc = {0,0,0,0};                                                  \
      sacc = __builtin_amdgcn_mfma_f32_16x16x32_bf16(qa0, kb0, sacc, 0, 0, 0);   \
      sacc = __builtin_amdgcn_mfma_f32_16x16x32_bf16(qa1, kb1, sacc, 0, 0, 0);   \
      _Pragma("unroll")                                                          \
      for (int r = 0; r < 4; ++r)                                                \
        Sqk[BUF][smt * 16 + kq * 4 + r][snt * 16 + fm] = sacc[r];                \
    }                                                                            \
  } while (0)

  rk = *(const uint4*)(kb);
  rv = *(const uint4*)(vb);
  *(uint4*)(&Ks[pr][pch]) = rk;
  *(uint4*)(&Vt[rV][cV]) = rv;
  __syncthreads();
  rk = *(const uint4*)(kb + (size_t)(32 + pr) * HID);
  rv = *(const uint4*)(vb + 32);
  {
    int rbase = KREL + i0 - 31;
    int r0 = rbase + brow_f;      if (r0 > 2047) r0 = 2047;
    int r1 = rbase + brow_f + 16; if (r1 > 2047) r1 = 2047;
    bhalf8 tA0 = *(const bhalf8*)(bgp + ((size_t)r0 << 10));
    bhalf8 tA1 = *(const bhalf8*)(bgp + ((size_t)r0 << 10) + 32);
    bhalf8 tB0 = *(const bhalf8*)(bgp + ((size_t)r1 << 10));
    bhalf8 tB1 = *(const bhalf8*)(bgp + ((size_t)r1 << 10) + 32);
    STAGE1(0, tA0, tA1, tB0, tB1);
  }
  __syncthreads();
  {
    *(uint4*)(&Ks[pr][pch]) = rk;
    rk = *(const uint4*)(kb + (size_t)(64 + pr) * HID);
    int rb1 = KREL + i0 - 63;
    int r0 = rb1 + brow_f;
    nbA0 = *(const bhalf8*)(bgp + ((size_t)r0 << 10));
    nbA1 = *(const bhalf8*)(bgp + ((size_t)r0 << 10) + 32);
    nbB0 = *(const bhalf8*)(bgp + ((size_t)(r0 + 16) << 10));
    nbB1 = *(const bhalf8*)(bgp + ((size_t)(r0 + 16) << 10) + 32);
  }
  __syncthreads();

  for (int jt = 0; jt < NSEQ / 32; ++jt) {
    int cur = jt & 1;

    float4 v_sqk = *(const float4*)(&Sqk[cur][i2][jj4]);
    float4 v_c2p = *(const float4*)(&C2Ps[cur][i2][jj4]);
    float p0 = P2C[cur][jj4 + 0][i2 - jj4 + 31];
    float p1 = P2C[cur][jj4 + 1][i2 - jj4 + 30];
    float p2 = P2C[cur][jj4 + 2][i2 - jj4 + 29];
    float p3 = P2C[cur][jj4 + 3][i2 - jj4 + 28];

    if (jt < 31) {
      int bi = cur ^ 1;
      STAGE1(bi, nbA0, nbA1, nbB0, nbB1);
    }

    {
      float sv0 = (v_sqk.x + v_c2p.x + p0) * RSCALE;
      float sv1 = (v_sqk.y + v_c2p.y + p1) * RSCALE;
      float sv2 = (v_sqk.z + v_c2p.z + p2) * RSCALE;
      float sv3 = (v_sqk.w + v_c2p.w + p3) * RSCALE;
      float mx = fmaxf(fmaxf(sv0, sv1), fmaxf(sv2, sv3));
      mx = fmaxf(mx, __shfl_xor(mx, 1));
      mx = fmaxf(mx, __shfl_xor(mx, 2));
      mx = fmaxf(mx, __shfl_xor(mx, 4));
      float m_old = m_sm[i2];
      float m_new = fmaxf(m_old, mx);
      float al = __expf(m_old - m_new);
      float e0 = __expf(sv0 - m_new);
      float e1 = __expf(sv1 - m_new);
      float e2 = __expf(sv2 - m_new);
      float e3 = __expf(sv3 - m_new);
      uint2 pk2v;
      pk2v.x = (uint32_t)f2bf(e0) | ((uint32_t)f2bf(e1) << 16);
      pk2v.y = (uint32_t)f2bf(e2) | ((uint32_t)f2bf(e3) << 16);
      *(uint2*)(&Pbf[i2][jj4]) = pk2v;
      float ts = (e0 + e1) + (e2 + e3);
      ts += __shfl_xor(ts, 1);
      ts += __shfl_xor(ts, 2);
      ts += __shfl_xor(ts, 4);
      if (jj4 == 0) { m_sm[i2] = m_new; l_sm[i2] = l_sm[i2] * al + ts; al_sm[i2] = al; }
    }
    __syncthreads();

    {
      floatx4 al0 = *(const floatx4*)(&al_sm[kq * 4]);
      floatx4 al1 = *(const floatx4*)(&al_sm[16 + kq * 4]);
#pragma unroll
      for (int r = 0; r < 4; ++r) {
        opv0[r] *= al0[r];
        opv1[r] *= al1[r];
      }
      bhalf8 vbf = *(bhalf8*)(&Vt[wn + fm][kq * 8]);
      bhalf8 pa0 = *(bhalf8*)(&Pbf[fm][kq * 8]);
      bhalf8 pa1 = *(bhalf8*)(&Pbf[16 + fm][kq * 8]);
      opv0 = __builtin_amdgcn_mfma_f32_16x16x32_bf16(pa0, vbf, opv0, 0, 0, 0);
      opv1 = __builtin_amdgcn_mfma_f32_16x16x32_bf16(pa1, vbf, opv1, 0, 0, 0);
      if (jt < 31) *(uint4*)(&Vt[rV][cV]) = rv;
      if (jt < 30) rv = *(const uint4*)(vb + (jt + 2) * 32);
    }
    if (jt < 30) {
      *(uint4*)(&Ks[pr][pch]) = rk;
    }
    if (jt < 29) {
      rk = *(const uint4*)(kb + (size_t)((jt + 3) * 32 + pr) * HID);
    }
    if (jt < 30) {
      int rb = KREL + i0 - (jt + 2) * 32 - 31;
      int r0 = rb + brow_f;
      nbA0 = *(const bhalf8*)(bgp + ((size_t)r0 << 10));
      nbA1 = *(const bhalf8*)(bgp + ((size_t)r0 << 10) + 32);
      nbB0 = *(const bhalf8*)(bgp + ((size_t)(r0 + 16) << 10));
      nbB1 = *(const bhalf8*)(bgp + ((size_t)(r0 + 16) << 10) + 32);
    }
    __syncthreads();
  }
#undef STAGE1

  {
    floatx4 l0 = *(const floatx4*)(&l_sm[kq * 4]);
    floatx4 l1 = *(const floatx4*)(&l_sm[16 + kq * 4]);
#pragma unroll
    for (int r = 0; r < 4; ++r) {
      int ia = kq * 4 + r, ib = 16 + kq * 4 + r;
      ctx[(size_t)(i0 + ia) * HID + cb + wn + fm] = f2bf(opv0[r] / l0[r]);
      ctx[(size_t)(i0 + ib) * HID + cb + wn + fm] = f2bf(opv1[r] / l1[r]);
    }
  }
}

// ---------------- residual + LayerNorm ----------------
__global__ __launch_bounds__(256) void ln_kernel(const float* __restrict__ xin,
                                                 const float* __restrict__ hs,
                                                 const float* __restrict__ g,
                                                 const float* __restrict__ b,
                                                 float* __restrict__ y) {
  int row = blockIdx.x, t = threadIdx.x;
  int c = t * 4;
  float4 a = *(const float4*)(xin + (size_t)row * HID + c);
  float4 hv = *(const float4*)(hs + (size_t)row * HID + c);
  float x0 = a.x + hv.x, x1 = a.y + hv.y, x2 = a.z + hv.z, x3 = a.w + hv.w;
  float s = x0 + x1 + x2 + x3;
  float sq = x0 * x0 + x1 * x1 + x2 * x2 + x3 * x3;
  for (int off = 32; off; off >>= 1) {
    s += __shfl_xor(s, off);
    sq += __shfl_xor(sq, off);
  }
  __shared__ float rs[4], rq[4];
  int w = t >> 6, lane = t & 63;
  if (lane == 0) { rs[w] = s; rq[w] = sq; }
  __syncthreads();
  s = rs[0] + rs[1] + rs[2] + rs[3];
  sq = rq[0] + rq[1] + rq[2] + rq[3];
  float mu = s * (1.0f / HID);
  float var = sq * (1.0f / HID) - mu * mu;
  float rstd = rsqrtf(var + 1e-7f);
  float4 gg = *(const float4*)(g + c);
  float4 bb = *(const float4*)(b + c);
  float4 out;
  out.x = (x0 - mu) * rstd * gg.x + bb.x;
  out.y = (x1 - mu) * rstd * gg.y + bb.y;
  out.z = (x2 - mu) * rstd * gg.z + bb.z;
  out.w = (x3 - mu) * rstd * gg.w + bb.w;
  *(float4*)(y + (size_t)row * HID + c) = out;
}

extern "C" void kernel_launch(void* const* d_in, const int* in_sizes, int n_in,
                              void* d_out, int out_size, void* d_ws, size_t ws_size,
                              hipStream_t stream) {
  const float* hs  = (const float*)d_in[0];
  const float* rel = (const float*)d_in[1];
  const float* Wq  = (const float*)d_in[2];  const float* bq  = (const float*)d_in[3];
  const float* Wk  = (const float*)d_in[4];  const float* bk  = (const float*)d_in[5];
  const float* Wv  = (const float*)d_in[6];  const float* bv  = (const float*)d_in[7];
  const float* Wpk = (const float*)d_in[8];  const float* bpk = (const float*)d_in[9];
  const float* Wpq = (const float*)d_in[10]; const float* bpq = (const float*)d_in[11];
  const float* Wo  = (const float*)d_in[12]; const float* bo  = (const float*)d_in[13];
  const float* lng = (const float*)d_in[14]; const float* lnb = (const float*)d_in[15];

  char* ws = (char*)d_ws;
  const size_t MB = 1024 * 1024;
  uint16_t* q_bf   = (uint16_t*)(ws + 0 * MB);
  uint16_t* k_bf   = (uint16_t*)(ws + 2 * MB);
  uint16_t* vt_bf  = (uint16_t*)(ws + 4 * MB);   // transposed [d][i]
  uint16_t* pk_bf  = (uint16_t*)(ws + 6 * MB);
  uint16_t* pq_bf  = (uint16_t*)(ws + 10 * MB);
  uint16_t* ctx_bf = (uint16_t*)(ws + 14 * MB);
  float*    out_f  = (float*)   (ws + 16 * MB);  // total 20 MB

  dim3 blk(256);

  ProjArgs pa;
  pa.A[0] = hs;  pa.A[1] = hs;  pa.A[2] = hs;  pa.A[3] = rel; pa.A[4] = rel;
  pa.W[0] = Wq;  pa.W[1] = Wk;  pa.W[2] = Wv;  pa.W[3] = Wpk; pa.W[4] = Wpq;
  pa.bias[0] = bq;  pa.bias[1] = bk;  pa.bias[2] = bv;  pa.bias[3] = bpk; pa.bias[4] = bpq;
  pa.C[0] = q_bf; pa.C[1] = k_bf; pa.C[2] = vt_bf; pa.C[3] = pk_bf; pa.C[4] = pq_bf;
  pa.trans[0] = 0; pa.trans[1] = 0; pa.trans[2] = 1; pa.trans[3] = 0; pa.trans[4] = 0;
  proj_gemm<<<dim3(448), dim3(512), 0, stream>>>(pa);

  attn_kernel<<<dim3(512), blk, 0, stream>>>(q_bf, k_bf, vt_bf, pk_bf, pq_bf, ctx_bf);

  out_gemm<<<dim3(256), blk, 0, stream>>>(ctx_bf, Wo, bo, out_f);

  ln_kernel<<<dim3(1024), blk, 0, stream>>>(out_f, hs, lng, lnb, (float*)d_out);
}